// Round 11
// baseline (1422.355 us; speedup 1.0000x reference)
//
#include <hip/hip_runtime.h>
#include <cstdio>

#define B_   256
#define H_   512
#define G4_  2048
#define T_   326
#define OUT_ 9

typedef __attribute__((ext_vector_type(8))) short s16x8;
typedef __attribute__((ext_vector_type(4))) float f32x4;
typedef unsigned long long ull;

__device__ inline unsigned short to_bf16(float f) {
    unsigned int u = __builtin_bit_cast(unsigned int, f);
    unsigned int r = (u + 0x7fffu + ((u >> 16) & 1u)) >> 16;  // RNE
    return (unsigned short)r;
}

__device__ inline float sigmoidf_(float x) { return 1.0f / (1.0f + __expf(-x)); }

__device__ inline float fast_tanh(float x) {
    x = fminf(fmaxf(x, -15.f), 15.f);
    float e = __expf(2.f * x);
    return (e - 1.f) / (e + 1.f);
}

// ---------------- prep kernels ----------------

__global__ void prep_weights(const float* __restrict__ Wih, const float* __restrict__ Whh,
                             const float* __restrict__ bih, const float* __restrict__ bhh,
                             unsigned short* __restrict__ Wc, unsigned short* __restrict__ Wcat,
                             float* __restrict__ bc) {
    int idx = blockIdx.x * 256 + threadIdx.x;      // < 2048*512
    int n = idx >> 9, k = idx & 511;
    float wi = Wih[idx], wh = Whh[idx];
    Wc[idx] = to_bf16(wi + wh);
    Wcat[(n << 10) + k]       = to_bf16(wi);
    Wcat[(n << 10) + 512 + k] = to_bf16(wh);
    if (k == 0) bc[n] = bih[n] + bhh[n];
}

__global__ void prep_w1(const float* __restrict__ W1, unsigned short* __restrict__ W1b) {
    int idx = blockIdx.x * 256 + threadIdx.x;      // < 512*512
    W1b[idx] = to_bf16(W1[idx]);
}

__global__ void prep_w2(const float* __restrict__ W2, unsigned short* __restrict__ W2b) {
    int idx = blockIdx.x * 256 + threadIdx.x;      // < 16*512
    int o = idx >> 9, k = idx & 511;
    W2b[idx] = (o < OUT_) ? to_bf16(W2[o * H_ + k]) : (unsigned short)0;
}

__global__ void prep_x(const float* __restrict__ x, const float* __restrict__ hx0,
                       unsigned short* __restrict__ xcat) {
    int idx = blockIdx.x * 256 + threadIdx.x;      // < 256*512
    int b = idx >> 9, k = idx & 511;
    xcat[(b << 10) + k]       = to_bf16(x[idx]);
    xcat[(b << 10) + 512 + k] = to_bf16(hx0[idx]);
}

// ---------------- step 0 (K=1024, [x|hx0] @ [Wih|Whh]) ----------------
template <int KLEN>
__global__ __launch_bounds__(256) void lstm_step(
    const unsigned short* __restrict__ A,
    const unsigned short* __restrict__ W,
    const float* __restrict__ bc,
    const float* __restrict__ c_in,
    float* __restrict__ c_out,
    unsigned short* __restrict__ h_out) {
    const int lane = threadIdx.x & 63;
    const int wave = threadIdx.x >> 6;
    const int mn = lane & 15, q = lane >> 4;
    const int rt = blockIdx.x & 15;
    const int hb = (blockIdx.x >> 4) * 64 + wave * 16;

    const unsigned short* ap  = A + (size_t)(rt * 16 + mn) * KLEN + q * 8;
    const unsigned short* wp0 = W + (size_t)(0 * H_ + hb + mn) * KLEN + q * 8;
    const unsigned short* wp1 = W + (size_t)(1 * H_ + hb + mn) * KLEN + q * 8;
    const unsigned short* wp2 = W + (size_t)(2 * H_ + hb + mn) * KLEN + q * 8;
    const unsigned short* wp3 = W + (size_t)(3 * H_ + hb + mn) * KLEN + q * 8;

    f32x4 acc0 = {0.f,0.f,0.f,0.f}, acc1 = {0.f,0.f,0.f,0.f};
    f32x4 acc2 = {0.f,0.f,0.f,0.f}, acc3 = {0.f,0.f,0.f,0.f};
#pragma unroll 4
    for (int k0 = 0; k0 < KLEN; k0 += 32) {
        s16x8 a  = *reinterpret_cast<const s16x8*>(ap + k0);
        s16x8 w0 = *reinterpret_cast<const s16x8*>(wp0 + k0);
        s16x8 w1 = *reinterpret_cast<const s16x8*>(wp1 + k0);
        s16x8 w2 = *reinterpret_cast<const s16x8*>(wp2 + k0);
        s16x8 w3 = *reinterpret_cast<const s16x8*>(wp3 + k0);
        acc0 = __builtin_amdgcn_mfma_f32_16x16x32_bf16(a, w0, acc0, 0, 0, 0);
        acc1 = __builtin_amdgcn_mfma_f32_16x16x32_bf16(a, w1, acc1, 0, 0, 0);
        acc2 = __builtin_amdgcn_mfma_f32_16x16x32_bf16(a, w2, acc2, 0, 0, 0);
        acc3 = __builtin_amdgcn_mfma_f32_16x16x32_bf16(a, w3, acc3, 0, 0, 0);
    }

    const int j = hb + mn;
    const float bi = bc[j], bfv = bc[H_ + j], bg = bc[2 * H_ + j], bo = bc[3 * H_ + j];
#pragma unroll
    for (int r = 0; r < 4; ++r) {
        const int row = rt * 16 + q * 4 + r;
        const float iv = sigmoidf_(acc0[r] + bi);
        const float fv = sigmoidf_(acc1[r] + bfv);
        const float gv = fast_tanh(acc2[r] + bg);
        const float ov = sigmoidf_(acc3[r] + bo);
        const float co = c_in[row * H_ + j];
        const float cn = fv * co + iv * gv;
        c_out[row * H_ + j] = cn;
        h_out[row * H_ + j] = to_bf16(ov * fast_tanh(cn));
    }
}

// -- persistent LSTM 8 groups x 32 rows (blocks 0..127) + consumers (128..255) --
// NORMAL launch, 256 blocks (~210 VGPR, 51KB LDS -> all blocks resident).
//  PERSIST (0..127): g = blockIdx&7 (one group per XCD, blockIdx%8 = g), 16
//    WGs per group = pool-16 (the PROVEN barrier size; target 16t verbatim
//    R3), wg = blockIdx>>3 owns 32 cols (jb = wg*32). M=32 rows as 2 MFMA
//    subtiles (R0's proven shape), breg[2][16] (R3's), XOR-swizzled A_lds,
//    gate exchange [4][32][36] f32, 4B packed h-stores (the width every
//    passing kernel used; 8B correlated with pool-8 failures).
//  CONSUMER (128..255): R9's verified role byte-identical modulo indices:
//    j = blockIdx-128, xcd = j&7 serves group g=xcd; item (t, half) maps to
//    gg = 2*xcd+half, rows [gg*16, +16) -- same M=16 staging/compute/output.
//    Poll ctr[xcd] >= 16t with s_sleep; plain stores to out.
__global__ __launch_bounds__(256) void lstm_persist(
    const unsigned short* __restrict__ Wc,   // [2048][512] bf16
    const float* __restrict__ bc,            // [2048]
    const float* __restrict__ c0,            // [256][512] f32 (from step 0)
    unsigned short* __restrict__ h_hist,     // [326][256][512] bf16
    unsigned int* __restrict__ ctr,          // 8 counters, 128B apart
    const unsigned short* __restrict__ W1b,  // [512][512] bf16
    const float* __restrict__ b1,            // [512]
    const unsigned short* __restrict__ W2b,  // [16][512] bf16 (rows 9..15 zero)
    const float* __restrict__ b2,            // [9]
    float* __restrict__ out) {               // [256][326][9] f32
    // LDS overlay: persist: A_lds [0,32768) + gate_lds [32768, 51200)
    //              consumer: A_lds [0,16384) + z_lds [16384, 49664)
    __shared__ ull smem[6400];                   // 51200 B
    unsigned short* A_lds = reinterpret_cast<unsigned short*>(smem);
    float* gate_lds = reinterpret_cast<float*>(reinterpret_cast<char*>(smem) + 32768);
    unsigned short* z_lds = reinterpret_cast<unsigned short*>(reinterpret_cast<char*>(smem) + 16384);
    const int tid = threadIdx.x;
    const int lane = tid & 63, wave = tid >> 6;
    const int mn = lane & 15, q = lane >> 4;

    // swizzled ushort indices (R3 formula). a_st covers 16 rows (2048 qwords);
    // rows 16..31 reuse a_st + 8192 (row+16 keeps row&7, so same XOR).
    int a_st[8];
#pragma unroll
    for (int p = 0; p < 8; ++p) {
        const int qi = p * 256 + tid;
        const int row = qi >> 7;                 // 128 qwords per 512-col row
        const int bcol = (qi & 127) * 8;
        a_st[p] = row * 512 + ((bcol ^ ((row & 7) << 4)) >> 1);
    }
    int a_rd[16];                                // rows mn; rows 16+mn = +8192
#pragma unroll
    for (int kk = 0; kk < 16; ++kk) {
        const int bcol = kk * 64 + q * 16;
        a_rd[kk] = mn * 512 + ((bcol ^ ((mn & 7) << 4)) >> 1);
    }

    if (blockIdx.x < 128) {
        // ================= PERSIST role =================
        const int g  = blockIdx.x & 7;           // group = XCD
        const int jb = (blockIdx.x >> 3) * 32;   // 32 cols per WG
        unsigned int* ctr_g = ctr + g * 32;      // own cacheline per group

        // weights -> registers (verbatim R3: wave = gate, two 16-col N-tiles)
        s16x8 breg[2][16];
#pragma unroll
        for (int n = 0; n < 2; ++n) {
            const unsigned short* wp = Wc + (size_t)(wave * H_ + jb + n * 16 + mn) * H_ + q * 8;
#pragma unroll
            for (int kk = 0; kk < 16; ++kk)
                breg[n][kk] = *reinterpret_cast<const s16x8*>(wp + kk * 32);
        }
        const float bcv0 = bc[wave * H_ + jb + mn];
        const float bcv1 = bc[wave * H_ + jb + 16 + mn];

        // owned c/h: row crow (0..31), 4 adjacent cols cc..cc+3
        const int crow = tid >> 3, cc = (tid & 7) * 4;
        f32x4 creg = *reinterpret_cast<const f32x4*>(&c0[(size_t)(g * 32 + crow) * H_ + jb + cc]);

        for (int t = 1; t < T_; ++t) {
            // ---- stage A = h_{t-1} rows [g*32, g*32+32): 2 batches of 8x8B ----
            const ull* hsrc64 = reinterpret_cast<const ull*>(
                h_hist + (size_t)(t - 1) * (B_ * H_) + (size_t)g * 32 * H_);
            {
                ull vv[8];
#pragma unroll
                for (int p = 0; p < 8; ++p)
                    vv[p] = __hip_atomic_load(hsrc64 + p * 256 + tid, __ATOMIC_RELAXED,
                                              __HIP_MEMORY_SCOPE_AGENT);
#pragma unroll
                for (int p = 0; p < 8; ++p)
                    *reinterpret_cast<ull*>(&A_lds[a_st[p]]) = vv[p];
#pragma unroll
                for (int p = 0; p < 8; ++p)
                    vv[p] = __hip_atomic_load(hsrc64 + 2048 + p * 256 + tid, __ATOMIC_RELAXED,
                                              __HIP_MEMORY_SCOPE_AGENT);
#pragma unroll
                for (int p = 0; p < 8; ++p)
                    *reinterpret_cast<ull*>(&A_lds[a_st[p] + 8192]) = vv[p];
            }
            __syncthreads();

            // ---- gates via MFMA (M=32 as 2 subtiles, N=2x16, K=512) ----
            f32x4 acc00 = {0.f,0.f,0.f,0.f}, acc01 = {0.f,0.f,0.f,0.f};
            f32x4 acc10 = {0.f,0.f,0.f,0.f}, acc11 = {0.f,0.f,0.f,0.f};
#pragma unroll
            for (int kk = 0; kk < 16; ++kk) {
                s16x8 a0 = *reinterpret_cast<const s16x8*>(&A_lds[a_rd[kk]]);
                s16x8 a1 = *reinterpret_cast<const s16x8*>(&A_lds[a_rd[kk] + 8192]);
                acc00 = __builtin_amdgcn_mfma_f32_16x16x32_bf16(a0, breg[0][kk], acc00, 0, 0, 0);
                acc01 = __builtin_amdgcn_mfma_f32_16x16x32_bf16(a0, breg[1][kk], acc01, 0, 0, 0);
                acc10 = __builtin_amdgcn_mfma_f32_16x16x32_bf16(a1, breg[0][kk], acc10, 0, 0, 0);
                acc11 = __builtin_amdgcn_mfma_f32_16x16x32_bf16(a1, breg[1][kk], acc11, 0, 0, 0);
            }

            // ---- activations -> gate LDS [gate][row 32][stride 36] ----
#pragma unroll
            for (int r = 0; r < 4; ++r) {
                float v00 = acc00[r] + bcv0, v01 = acc01[r] + bcv1;
                float v10 = acc10[r] + bcv0, v11 = acc11[r] + bcv1;
                if (wave == 2) { v00 = fast_tanh(v00); v01 = fast_tanh(v01);
                                 v10 = fast_tanh(v10); v11 = fast_tanh(v11); }
                else           { v00 = sigmoidf_(v00); v01 = sigmoidf_(v01);
                                 v10 = sigmoidf_(v10); v11 = sigmoidf_(v11); }
                const int r0 = wave * 1152 + (q * 4 + r) * 36;        // rows 0..15
                gate_lds[r0 + mn]            = v00;
                gate_lds[r0 + 16 + mn]       = v01;
                gate_lds[r0 + 576 + mn]      = v10;                   // rows 16..31
                gate_lds[r0 + 576 + 16 + mn] = v11;
            }
            __syncthreads();

            // ---- c/h update (4 adjacent cols of one row per thread) ----
            {
                f32x4 iv = *reinterpret_cast<const f32x4*>(&gate_lds[0 * 1152 + crow * 36 + cc]);
                f32x4 fv = *reinterpret_cast<const f32x4*>(&gate_lds[1 * 1152 + crow * 36 + cc]);
                f32x4 gv = *reinterpret_cast<const f32x4*>(&gate_lds[2 * 1152 + crow * 36 + cc]);
                f32x4 ov = *reinterpret_cast<const f32x4*>(&gate_lds[3 * 1152 + crow * 36 + cc]);
                unsigned int hp[2];
#pragma unroll
                for (int jj = 0; jj < 2; ++jj) {
                    float cn0 = fv[2*jj] * creg[2*jj] + iv[2*jj] * gv[2*jj];
                    float cn1 = fv[2*jj+1] * creg[2*jj+1] + iv[2*jj+1] * gv[2*jj+1];
                    creg[2*jj] = cn0; creg[2*jj+1] = cn1;
                    unsigned int h0 = to_bf16(ov[2*jj] * fast_tanh(cn0));
                    unsigned int h1 = to_bf16(ov[2*jj+1] * fast_tanh(cn1));
                    hp[jj] = h0 | (h1 << 16);
                }
                unsigned int* hdst = reinterpret_cast<unsigned int*>(
                    h_hist + (size_t)t * (B_ * H_) + (size_t)(g * 32 + crow) * H_ + jb + cc);
                __hip_atomic_store(hdst,     hp[0], __ATOMIC_RELAXED, __HIP_MEMORY_SCOPE_AGENT);
                __hip_atomic_store(hdst + 1, hp[1], __ATOMIC_RELAXED, __HIP_MEMORY_SCOPE_AGENT);
            }

            // ---- per-group barrier (16 WGs, verbatim R3); publish EVERY step ----
            __syncthreads();  // emits s_waitcnt vmcnt(0): sc1 h-stores complete
            asm volatile("" ::: "memory");
            if (tid == 0) {
                __hip_atomic_fetch_add(ctr_g, 1u, __ATOMIC_RELAXED, __HIP_MEMORY_SCOPE_AGENT);
                if (t < T_ - 1) {
                    const unsigned int target = 16u * (unsigned int)t;
                    while (__hip_atomic_load(ctr_g, __ATOMIC_RELAXED,
                                             __HIP_MEMORY_SCOPE_AGENT) < target) {
                    }
                }
            }
            asm volatile("" ::: "memory");
            if (t < T_ - 1) __syncthreads();
        }
    } else {
        // ================= MLP consumer role (R9 verified) =================
        const int j = blockIdx.x - 128;              // 0..127
        const int xcd = j & 7, mid = j >> 3;         // serves group g = xcd

        float b1v[8];
#pragma unroll
        for (int nt = 0; nt < 8; ++nt) b1v[nt] = b1[wave * 128 + nt * 16 + mn];
        const float b2v = (mn < OUT_) ? b2[mn] : 0.f;

        // items: i in [0, 652), t = i>>1, half = i&1, gg = 2*xcd + half
        for (int i = mid; i < 2 * T_; i += 16) {
            const int t = i >> 1;
            const int gg = 2 * xcd + (i & 1);

            if (tid == 0) {
                const unsigned int tgt = 16u * (unsigned int)t;
                while (__hip_atomic_load(ctr + xcd * 32, __ATOMIC_RELAXED,
                                         __HIP_MEMORY_SCOPE_AGENT) < tgt)
                    __builtin_amdgcn_s_sleep(4);
            }
            __syncthreads();

            // ---- stage h_t rows [gg*16, gg*16+16) (same swizzled path) ----
            const ull* hsrc64 = reinterpret_cast<const ull*>(
                h_hist + (size_t)t * (B_ * H_) + (size_t)gg * 16 * H_);
            ull vv[8];
#pragma unroll
            for (int p = 0; p < 8; ++p)
                vv[p] = __hip_atomic_load(hsrc64 + p * 256 + tid, __ATOMIC_RELAXED,
                                          __HIP_MEMORY_SCOPE_AGENT);
#pragma unroll
            for (int p = 0; p < 8; ++p)
                *reinterpret_cast<ull*>(&A_lds[a_st[p]]) = vv[p];
            __syncthreads();

            // ---- z = relu(h @ W1^T + b1): M=16, wave owns 128 z-cols ----
            f32x4 acc[8];
#pragma unroll
            for (int nt = 0; nt < 8; ++nt) acc[nt] = f32x4{0.f,0.f,0.f,0.f};
            for (int kk = 0; kk < 16; ++kk) {
                s16x8 a = *reinterpret_cast<const s16x8*>(&A_lds[a_rd[kk]]);
#pragma unroll
                for (int nt = 0; nt < 8; ++nt) {
                    s16x8 b = *reinterpret_cast<const s16x8*>(
                        W1b + (size_t)(wave * 128 + nt * 16 + mn) * H_ + kk * 32 + q * 8);
                    acc[nt] = __builtin_amdgcn_mfma_f32_16x16x32_bf16(a, b, acc[nt], 0, 0, 0);
                }
            }
#pragma unroll
            for (int nt = 0; nt < 8; ++nt)
#pragma unroll
                for (int r = 0; r < 4; ++r) {
                    float v = acc[nt][r] + b1v[nt];
                    v = v > 0.f ? v : 0.f;
                    z_lds[(q * 4 + r) * 520 + wave * 128 + nt * 16 + mn] = to_bf16(v);
                }
            __syncthreads();

            // ---- y = z @ W2^T + b2 (wave 0), plain stores to out ----
            if (wave == 0) {
                f32x4 y = {0.f,0.f,0.f,0.f};
#pragma unroll 4
                for (int k0 = 0; k0 < 512; k0 += 32) {
                    s16x8 az = *reinterpret_cast<const s16x8*>(&z_lds[mn * 520 + k0 + q * 8]);
                    s16x8 bw = *reinterpret_cast<const s16x8*>(W2b + (size_t)mn * H_ + k0 + q * 8);
                    y = __builtin_amdgcn_mfma_f32_16x16x32_bf16(az, bw, y, 0, 0, 0);
                }
                if (mn < OUT_) {
#pragma unroll
                    for (int r = 0; r < 4; ++r)
                        out[(size_t)(gg * 16 + q * 4 + r) * (T_ * OUT_) + t * OUT_ + mn] = y[r] + b2v;
                }
            }
            __syncthreads();
        }
    }
}

// ---------------- host launch ----------------
extern "C" void kernel_launch(void* const* d_in, const int* in_sizes, int n_in,
                              void* d_out, int out_size, void* d_ws, size_t ws_size,
                              hipStream_t stream) {
    (void)in_sizes; (void)n_in; (void)out_size;
    const float* x   = (const float*)d_in[0];
    const float* hx0 = (const float*)d_in[1];
    const float* cx0 = (const float*)d_in[2];
    const float* Wih = (const float*)d_in[3];
    const float* Whh = (const float*)d_in[4];
    const float* bih = (const float*)d_in[5];
    const float* bhh = (const float*)d_in[6];
    const float* W1  = (const float*)d_in[7];
    const float* b1  = (const float*)d_in[8];
    const float* W2  = (const float*)d_in[9];
    const float* b2  = (const float*)d_in[10];
    float* out = (float*)d_out;

    char* p = (char*)d_ws;
    size_t off = 0;
    auto alloc = [&](size_t bytes) {
        void* r = p + off;
        off = (off + bytes + 255) & ~(size_t)255;
        return r;
    };
    unsigned short* Wc     = (unsigned short*)alloc((size_t)G4_ * H_ * 2);
    unsigned short* Wcat   = (unsigned short*)alloc((size_t)G4_ * 1024 * 2);
    unsigned short* W1b    = (unsigned short*)alloc((size_t)H_ * H_ * 2);
    unsigned short* W2b    = (unsigned short*)alloc((size_t)16 * H_ * 2);
    float*          bc     = (float*)alloc((size_t)G4_ * 4);
    unsigned short* xcat   = (unsigned short*)alloc((size_t)B_ * 1024 * 2);
    float*          cbuf   = (float*)alloc((size_t)B_ * H_ * 4);
    unsigned int*   ctr    = (unsigned int*)alloc(4096);
    unsigned short* h_hist = (unsigned short*)alloc((size_t)T_ * B_ * H_ * 2);
    if (off > ws_size) {
        fprintf(stderr, "kernel_launch: ws too small: need %zu have %zu\n", off, ws_size);
        return;
    }

    prep_weights<<<G4_ * H_ / 256, 256, 0, stream>>>(Wih, Whh, bih, bhh, Wc, Wcat, bc);
    prep_w1<<<H_ * H_ / 256, 256, 0, stream>>>(W1, W1b);
    prep_w2<<<16 * H_ / 256, 256, 0, stream>>>(W2, W2b);
    prep_x<<<B_ * H_ / 256, 256, 0, stream>>>(x, hx0, xcat);

    // step 0: K=1024
    lstm_step<1024><<<128, 256, 0, stream>>>(xcat, Wcat, bc, cx0, cbuf, h_hist);

    // zero group counters, then persist (128 WGs) + consumers (128 WGs)
    hipMemsetAsync(ctr, 0, 4096, stream);
    lstm_persist<<<256, 256, 0, stream>>>(Wc, bc, cbuf, h_hist, ctr,
                                          W1b, b1, W2b, b2, out);
}